// Round 1
// baseline (16236.186 us; speedup 1.0000x reference)
//
#include <hip/hip_runtime.h>
#include <hip/hip_bf16.h>

// Problem constants (from the reference)
#define N_NODES 20000
#define F_DIM   512
#define H_DIM   128
#define C_DIM   64
#define E_EDGES 640000

// ---------------- workspace layout (float offsets from d_ws) ----------------
// flag: int at word 0 (1 = inputs are f32, 0 = inputs are bf16)
#define P_WV1   64                      // 9 floats
#define P_B1    80                      // 384 floats
#define P_WV2   464                     // 9
#define P_B2    480                     // 192 -> ends 672
#define P_E     1024                    // 3 * N*H (layer-2 reuses with N*C stride)
#define P_ACC   (P_E + 3*N_NODES*H_DIM) // N*H
#define P_H     (P_ACC + N_NODES*H_DIM) // 3 * N*H
#define P_YSUM  (P_H + 3*N_NODES*H_DIM) // N*C
// total ~19.2M floats = ~74 MB

__device__ inline float cvt(float x) { return x; }
__device__ inline float cvt(__hip_bfloat16 x) { return __bfloat162float(x); }

__device__ inline void store_out(float v, float* p) { *p = v; }
__device__ inline void store_out(float v, __hip_bfloat16* p) { *p = __float2bfloat16(v); }

// ---------------- dtype probe ----------------
// If x1 is fp32, the even-index u16 words are mantissa low bits (uniform), so
// ~45% decode (as bf16) with exponent >= 140 (|x| >= 2^13). If x1 is bf16
// N(0,1) data, none do.
__global__ void detect_kernel(const unsigned short* __restrict__ x, int* flag) {
    __shared__ int cnt;
    if (threadIdx.x == 0) cnt = 0;
    __syncthreads();
    int c = 0;
    for (int i = threadIdx.x; i < 4096; i += 256) {
        int ex = (x[i] >> 7) & 0xff;
        if (ex >= 140) c++;
    }
    atomicAdd(&cnt, c);
    __syncthreads();
    if (threadIdx.x == 0) *flag = (cnt > 64) ? 1 : 0;
}

// Convert the small params (wv1,b1,wv2,b2) to fp32 in ws.
__global__ void prep_kernel(const int* __restrict__ flag,
                            const void* wv1, const void* b1,
                            const void* wv2, const void* b2, float* ws) {
    bool f32 = (*flag == 1);
    int t = threadIdx.x;
    auto get = [&](const void* p, int i) -> float {
        return f32 ? ((const float*)p)[i]
                   : __bfloat162float(((const __hip_bfloat16*)p)[i]);
    };
    if (t < 9) ws[P_WV1 + t] = get(wv1, t);
    if (t < 9) ws[P_WV2 + t] = get(wv2, t);
    for (int i = t; i < 3*H_DIM; i += 256) ws[P_B1 + i] = get(b1, i);
    for (int i = t; i < 3*C_DIM; i += 256) ws[P_B2 + i] = get(b2, i);
}

// ---------------- GEMM: out[N,HO] = X[N,K] @ W[K,HO], fp32 accumulate -------
// 64x64 tile, 4x4 register blocking, K-chunk 32. LDS is k-major so the inner
// loop is two ds_read_b128 per 16 FMAs.
template <typename TX, typename TW>
__global__ __launch_bounds__(256)
void gemm_kernel(const int* __restrict__ flag, int want,
                 const TX* __restrict__ X, const TW* __restrict__ W,
                 float* __restrict__ out, int n, int K, int HO) {
    if (*flag != want) return;
    __shared__ __align__(16) float Xs[32][68];  // [k][row], 272B stride (16B mult)
    __shared__ __align__(16) float Ws[32][68];  // [k][col]
    const int row0 = blockIdx.x * 64;
    const int col0 = blockIdx.y * 64;
    const int t = threadIdx.x;
    const int tx = t & 15, ty = t >> 4;
    float acc[4][4] = {};
    for (int k0 = 0; k0 < K; k0 += 32) {
        #pragma unroll
        for (int i = 0; i < 8; ++i) {            // X tile: 64 rows x 32 k
            int idx = t + i * 256;
            int r = idx >> 5, c = idx & 31;      // consecutive t -> consecutive k
            int gr = row0 + r;
            Xs[c][r] = (gr < n) ? cvt(X[(long)gr * K + k0 + c]) : 0.f;
        }
        #pragma unroll
        for (int i = 0; i < 8; ++i) {            // W tile: 32 k x 64 cols
            int idx = t + i * 256;
            int r = idx >> 6, c = idx & 63;      // consecutive t -> consecutive col
            Ws[r][c] = cvt(W[(long)(k0 + r) * HO + col0 + c]);
        }
        __syncthreads();
        #pragma unroll 8
        for (int kk = 0; kk < 32; ++kk) {
            float4 a4 = *(const float4*)&Xs[kk][ty * 4];
            float4 b4 = *(const float4*)&Ws[kk][tx * 4];
            float a[4] = {a4.x, a4.y, a4.z, a4.w};
            float b[4] = {b4.x, b4.y, b4.z, b4.w};
            #pragma unroll
            for (int i = 0; i < 4; ++i)
                #pragma unroll
                for (int j = 0; j < 4; ++j)
                    acc[i][j] += a[i] * b[j];
        }
        __syncthreads();
    }
    #pragma unroll
    for (int i = 0; i < 4; ++i) {
        int gr = row0 + ty * 4 + i;
        if (gr < n) {
            float4 o = {acc[i][0], acc[i][1], acc[i][2], acc[i][3]};
            *(float4*)&out[(long)gr * HO + col0 + tx * 4] = o;
        }
    }
}

// ---------------- SPMM scatter: acc[src[e]] += 1.01*wv*val[e]*E[dst[e]] -----
// HO = 4 << pshift (128 or 64). One thread per (edge, 4 features).
template <typename TV>
__global__ __launch_bounds__(256)
void scatter_kernel(const int* __restrict__ flag, int want,
                    const int* __restrict__ src, const int* __restrict__ dst,
                    const TV* __restrict__ val, const float* __restrict__ Etab,
                    float* __restrict__ acc, const float* __restrict__ wvp,
                    int pshift) {
    if (*flag != want) return;
    const int HO = 4 << pshift;
    long id = (long)blockIdx.x * 256 + threadIdx.x;
    int e = (int)(id >> pshift);
    int f = ((int)id & ((1 << pshift) - 1)) << 2;
    if (e >= E_EDGES) return;
    float scale = 1.01f * wvp[0] * cvt(val[e]);
    int d = dst[e], s = src[e];
    float4 v = *(const float4*)&Etab[(long)d * HO + f];
    float* o = &acc[(long)s * HO + f];
    atomicAdd(o + 0, scale * v.x);
    atomicAdd(o + 1, scale * v.y);
    atomicAdd(o + 2, scale * v.z);
    atomicAdd(o + 3, scale * v.w);
}

// h = relu(E0 + acc + b[col])
__global__ __launch_bounds__(256)
void combine1_kernel(const float* __restrict__ E0, const float* __restrict__ acc,
                     const float* __restrict__ b, float* __restrict__ h,
                     int n, int colmask) {
    int i = blockIdx.x * 256 + threadIdx.x;
    if (i >= n) return;
    float x = E0[i] + acc[i] + b[i & colmask];
    h[i] = x > 0.f ? x : 0.f;
}

// ysum (+)= relu(E0 + acc + b[col])
__global__ __launch_bounds__(256)
void combine2_kernel(const float* __restrict__ E0, const float* __restrict__ acc,
                     const float* __restrict__ b, float* __restrict__ ysum,
                     int n, int colmask, int first) {
    int i = blockIdx.x * 256 + threadIdx.x;
    if (i >= n) return;
    float x = E0[i] + acc[i] + b[i & colmask];
    x = x > 0.f ? x : 0.f;
    ysum[i] = first ? x : ysum[i] + x;
}

template <typename TOUT>
__global__ __launch_bounds__(256)
void final_kernel(const int* __restrict__ flag, int want,
                  const float* __restrict__ ysum, TOUT* __restrict__ out, int n) {
    if (*flag != want) return;
    int i = blockIdx.x * 256 + threadIdx.x;
    if (i >= n) return;
    store_out(fabsf(ysum[i] * (1.f / 3.f)), &out[i]);
}

extern "C" void kernel_launch(void* const* d_in, const int* in_sizes, int n_in,
                              void* d_out, int out_size, void* d_ws, size_t ws_size,
                              hipStream_t stream) {
    float* ws = (float*)d_ws;
    int* flag = (int*)d_ws;
    // xs/adjs permutation per view v: perm[v][r] = which x / adjacency feeds role r
    static const int perm[3][3] = {{0, 1, 2}, {1, 0, 2}, {2, 0, 1}};

    detect_kernel<<<1, 256, 0, stream>>>((const unsigned short*)d_in[0], flag);
    prep_kernel<<<1, 256, 0, stream>>>(flag, d_in[13], d_in[14], d_in[16], d_in[17], ws);

    // ---------------- layer 1: x -> h (H=128) ----------------
    for (int v = 0; v < 3; ++v) {
        for (int r = 0; r < 3; ++r) {
            int j = perm[v][r];
            long woff = (long)(v * 3 + r) * F_DIM * H_DIM;
            float* Er = ws + P_E + (long)r * N_NODES * H_DIM;
            dim3 g((N_NODES + 63) / 64, H_DIM / 64);
            gemm_kernel<__hip_bfloat16, __hip_bfloat16><<<g, 256, 0, stream>>>(
                flag, 0, (const __hip_bfloat16*)d_in[j],
                (const __hip_bfloat16*)d_in[12] + woff, Er, N_NODES, F_DIM, H_DIM);
            gemm_kernel<float, float><<<g, 256, 0, stream>>>(
                flag, 1, (const float*)d_in[j],
                (const float*)d_in[12] + woff, Er, N_NODES, F_DIM, H_DIM);
        }
        hipMemsetAsync(ws + P_ACC, 0, (size_t)N_NODES * H_DIM * 4, stream);
        for (int r = 0; r < 3; ++r) {
            int j = perm[v][r];
            const int* src = (const int*)d_in[3 + 3 * j];
            const int* dst = (const int*)d_in[4 + 3 * j];
            const float* Er = ws + P_E + (long)r * N_NODES * H_DIM;
            int blocks = E_EDGES * (H_DIM / 4) / 256;
            scatter_kernel<__hip_bfloat16><<<blocks, 256, 0, stream>>>(
                flag, 0, src, dst, (const __hip_bfloat16*)d_in[5 + 3 * j], Er,
                ws + P_ACC, ws + P_WV1 + v * 3 + r, 5);
            scatter_kernel<float><<<blocks, 256, 0, stream>>>(
                flag, 1, src, dst, (const float*)d_in[5 + 3 * j], Er,
                ws + P_ACC, ws + P_WV1 + v * 3 + r, 5);
        }
        combine1_kernel<<<(N_NODES * H_DIM) / 256, 256, 0, stream>>>(
            ws + P_E, ws + P_ACC, ws + P_B1 + v * H_DIM,
            ws + P_H + (long)v * N_NODES * H_DIM, N_NODES * H_DIM, H_DIM - 1);
    }

    // ---------------- layer 2: h -> y (C=64), accumulate ysum ----------------
    for (int v = 0; v < 3; ++v) {
        for (int r = 0; r < 3; ++r) {
            int j = perm[v][r];
            const float* Xh = ws + P_H + (long)j * N_NODES * H_DIM;
            long woff = (long)(v * 3 + r) * H_DIM * C_DIM;
            float* Er = ws + P_E + (long)r * N_NODES * C_DIM;
            dim3 g((N_NODES + 63) / 64, C_DIM / 64);
            gemm_kernel<float, __hip_bfloat16><<<g, 256, 0, stream>>>(
                flag, 0, Xh, (const __hip_bfloat16*)d_in[15] + woff, Er,
                N_NODES, H_DIM, C_DIM);
            gemm_kernel<float, float><<<g, 256, 0, stream>>>(
                flag, 1, Xh, (const float*)d_in[15] + woff, Er,
                N_NODES, H_DIM, C_DIM);
        }
        hipMemsetAsync(ws + P_ACC, 0, (size_t)N_NODES * C_DIM * 4, stream);
        for (int r = 0; r < 3; ++r) {
            int j = perm[v][r];
            const int* src = (const int*)d_in[3 + 3 * j];
            const int* dst = (const int*)d_in[4 + 3 * j];
            const float* Er = ws + P_E + (long)r * N_NODES * C_DIM;
            int blocks = E_EDGES * (C_DIM / 4) / 256;
            scatter_kernel<__hip_bfloat16><<<blocks, 256, 0, stream>>>(
                flag, 0, src, dst, (const __hip_bfloat16*)d_in[5 + 3 * j], Er,
                ws + P_ACC, ws + P_WV2 + v * 3 + r, 4);
            scatter_kernel<float><<<blocks, 256, 0, stream>>>(
                flag, 1, src, dst, (const float*)d_in[5 + 3 * j], Er,
                ws + P_ACC, ws + P_WV2 + v * 3 + r, 4);
        }
        combine2_kernel<<<(N_NODES * C_DIM) / 256, 256, 0, stream>>>(
            ws + P_E, ws + P_ACC, ws + P_B2 + v * C_DIM, ws + P_YSUM,
            N_NODES * C_DIM, C_DIM - 1, v == 0);
    }

    final_kernel<__hip_bfloat16><<<(out_size + 255) / 256, 256, 0, stream>>>(
        flag, 0, ws + P_YSUM, (__hip_bfloat16*)d_out, out_size);
    final_kernel<float><<<(out_size + 255) / 256, 256, 0, stream>>>(
        flag, 1, ws + P_YSUM, (float*)d_out, out_size);
}